// Round 1
// baseline (252.846 us; speedup 1.0000x reference)
//
#include <hip/hip_runtime.h>
#include <hip/hip_bf16.h>
#include <cstdint>
#include <cstddef>

// Problem constants (fixed by reference)
#define BB 32
#define NN 8192
#define DIN 64
#define DOUT 128
#define NR 4
#define BN_EPS 1e-5f

typedef float nfloat4 __attribute__((ext_vector_type(4)));
typedef float floatx4 __attribute__((ext_vector_type(4)));
typedef short short8 __attribute__((ext_vector_type(8)));

// Workspace: [0, 64KB) uint smax_keys[B*NR*128]
// (memset 0 each launch; key 0 decodes below any real value's key)

__device__ inline void pack2(float a, float b, short8& dst, int idx) {
  // packed f32x2 -> bf16x2 (compiler emits v_cvt_pk_bf16_f32 on gfx950)
  __hip_bfloat162 h = __float22bfloat162_rn(make_float2(a, b));
  const unsigned int bits = *(unsigned int*)&h;
  dst[idx] = (short)(bits & 0xffffu);
  dst[idx + 1] = (short)(bits >> 16);
}

// global -> LDS direct DMA (width must be a literal constant)
__device__ inline void gload_lds16(const void* g, void* l) {
  __builtin_amdgcn_global_load_lds(
      (const __attribute__((address_space(1))) unsigned int*)g,
      (__attribute__((address_space(3))) unsigned int*)l, 16, 0, 0);
}
__device__ inline void gload_lds4(const void* g, void* l) {
  __builtin_amdgcn_global_load_lds(
      (const __attribute__((address_space(1))) unsigned int*)g,
      (__attribute__((address_space(3))) unsigned int*)l, 4, 0, 0);
}

// ---------------------------------------------------------------------------
// K1 (MFMA): block = (b, 256-point chunk), 4 waves. Wave w owns channel tiles
// {w, w+4}. x-tile is staged global->LDS via global_load_lds dwordx4 in 64-pt
// sub-tiles, double-buffered; LDS stores f32 rows [d][64 n] with the SOURCE
// column pre-swizzled c ^ ((d>>3&3)<<3) so the along-d fragment reads are
// bank-conflict-free (2 lanes/bank) while the DMA destination stays linear
// (rule: swizzle both sides or neither). ring[] pre-staged to LDS (per-T read
// is a same-address broadcast). Per-ring segment max via register masks, then
// 16-point butterfly + one atomicMax per (ring, chan).
__global__ void __launch_bounds__(256) k_compute(
    const float* __restrict__ x, const float* __restrict__ W,
    const int* __restrict__ ring, unsigned int* __restrict__ smax_keys) {
  const int b = blockIdx.y;
  const int n0 = blockIdx.x * 256;
  const int tid = (int)threadIdx.x;
  const int wave = tid >> 6;
  const int lane = tid & 63;
  const int quad = lane >> 4;
  const int l16 = lane & 15;
  const float* xb = x + (size_t)b * DIN * NN;

  __shared__ float lx[2][DIN * 64];  // 2 x 16 KB double buffer, row = 64 floats
  __shared__ int lring[256];

  // ---- prologue: stage ring chunk (1 DMA/wave) + x sub-tile 0
  gload_lds4(ring + (size_t)b * NN + n0 + wave * 64 + lane, &lring[wave * 64]);

  // stage x sub-tile s into lx[pbuf]: 4 DMA instrs per wave, 1 KB each.
  // lane l covers LDS row d = wave*16 + i*4 + (l>>4), float cols (l&15)*4..+3;
  // global source column is XOR-swizzled so reads can un-swizzle.
  auto stage = [&](int pbuf, int s) {
    const int ns0 = n0 + s * 64;
#pragma unroll
    for (int i = 0; i < 4; ++i) {
      const int d = wave * 16 + i * 4 + (lane >> 4);
      const int c0 = (lane & 15) * 4;
      const int cg = c0 ^ (((d >> 3) & 3) << 3);
      gload_lds16(xb + (size_t)d * NN + ns0 + cg,
                  &lx[pbuf][(wave * 16 + i * 4) * 64]);
    }
  };
  stage(0, 0);

  // A fragments for all 4 rings: afr[r][tile][kstep], A[m=l16][k=quad*8+j].
  // 4r x 2t x 2ks x 4 VGPR = 64 VGPR of bf16 W data (L1-served float4 loads).
  short8 afr[NR][2][2];
#pragma unroll
  for (int r = 0; r < NR; ++r) {
#pragma unroll
    for (int tt = 0; tt < 2; ++tt) {
      const int chan = (wave + 4 * tt) * 16 + l16;
      const float* wr = W + ((size_t)r * DOUT + chan) * DIN + quad * 8;
#pragma unroll
      for (int ks = 0; ks < 2; ++ks) {
        const float4 w0 = *(const float4*)&wr[ks * 32];
        const float4 w1 = *(const float4*)&wr[ks * 32 + 4];
        short8 a;
        pack2(w0.x, w0.y, a, 0);
        pack2(w0.z, w0.w, a, 2);
        pack2(w1.x, w1.y, a, 4);
        pack2(w1.z, w1.w, a, 6);
        afr[r][tt][ks] = a;
      }
    }
  }

  floatx4 rmax[2][NR];
#pragma unroll
  for (int tt = 0; tt < 2; ++tt)
#pragma unroll
    for (int r = 0; r < NR; ++r)
      rmax[tt][r] = {-INFINITY, -INFINITY, -INFINITY, -INFINITY};

  __syncthreads();  // drains prologue DMA (ring + sub-tile 0)

#pragma unroll 1
  for (int s = 0; s < 4; ++s) {
    if (s < 3) stage((s + 1) & 1, s + 1);  // DMA next sub-tile, overlaps compute
    const float* lbuf = lx[s & 1];
#pragma unroll
    for (int T = 0; T < 4; ++T) {
      const int nl = T * 16 + l16;          // point col within sub-tile
      const int csw = nl ^ (quad * 8);      // un-swizzle (same for all 16 reads)
      const int rr = lring[s * 64 + nl];    // broadcast LDS read
      // 4 read clusters, dword offsets {0,64,128,192} -> ds_read2_b32 pairs
      const float* p0 = &lbuf[(quad * 8) * 64 + csw];
      const float* p1 = &lbuf[(quad * 8 + 4) * 64 + csw];
      const float* p2 = &lbuf[(32 + quad * 8) * 64 + csw];
      const float* p3 = &lbuf[(32 + quad * 8 + 4) * 64 + csw];
      float v0[8], v1[8];
#pragma unroll
      for (int j = 0; j < 4; ++j) {
        v0[j] = p0[j * 64];
        v0[4 + j] = p1[j * 64];
        v1[j] = p2[j * 64];
        v1[4 + j] = p3[j * 64];
      }
      short8 b0, b1;
#pragma unroll
      for (int j = 0; j < 4; ++j) {
        pack2(v0[2 * j], v0[2 * j + 1], b0, 2 * j);
        pack2(v1[2 * j], v1[2 * j + 1], b1, 2 * j);
      }
#pragma unroll
      for (int r = 0; r < NR; ++r) {
        floatx4 acc0 = {0.f, 0.f, 0.f, 0.f};
        floatx4 acc1 = {0.f, 0.f, 0.f, 0.f};
        acc0 = __builtin_amdgcn_mfma_f32_16x16x32_bf16(afr[r][0][0], b0, acc0, 0, 0, 0);
        acc0 = __builtin_amdgcn_mfma_f32_16x16x32_bf16(afr[r][0][1], b1, acc0, 0, 0, 0);
        acc1 = __builtin_amdgcn_mfma_f32_16x16x32_bf16(afr[r][1][0], b0, acc1, 0, 0, 0);
        acc1 = __builtin_amdgcn_mfma_f32_16x16x32_bf16(afr[r][1][1], b1, acc1, 0, 0, 0);
        const bool m = (rr == r);
#pragma unroll
        for (int p = 0; p < 4; ++p) {
          rmax[0][r][p] = fmaxf(rmax[0][r][p], m ? acc0[p] : -INFINITY);
          rmax[1][r][p] = fmaxf(rmax[1][r][p], m ? acc1[p] : -INFINITY);
        }
      }
    }
    if (s < 3) __syncthreads();  // vmcnt(0) drain == next sub-tile ready
  }

  // reduce over the 16 point-columns (lane bits 0-3); one atomic per
  // (ring, chan) from the l16==0 lane of each quad.
#pragma unroll
  for (int tt = 0; tt < 2; ++tt) {
#pragma unroll
    for (int r = 0; r < NR; ++r) {
#pragma unroll
      for (int p = 0; p < 4; ++p) {
        float v = rmax[tt][r][p];
        v = fmaxf(v, __shfl_xor(v, 1, 64));
        v = fmaxf(v, __shfl_xor(v, 2, 64));
        v = fmaxf(v, __shfl_xor(v, 4, 64));
        v = fmaxf(v, __shfl_xor(v, 8, 64));
        if (l16 == 0) {
          const int chan = (wave + 4 * tt) * 16 + quad * 4 + p;
          const unsigned int u = __float_as_uint(v);
          const unsigned int key = (u & 0x80000000u) ? ~u : (u | 0x80000000u);
          atomicMax(&smax_keys[(size_t)(b * NR + r) * DOUT + chan], key);
        }
      }
    }
  }
}

// ---------------------------------------------------------------------------
// K2: finalize affine on the 16K maxima, then broadcast to output:
// out[b][o][n] = ymax[b][ring[b,n]][o].
// The old per-lane gather ymax[oo*4+rg] was a 16-way LDS bank conflict (all
// 64 lanes in 4 consecutive banks). Replaced by ONE wave-uniform ds_read_b128
// per channel (same-address broadcast = conflict-free) + a 3-cndmask select
// tree per component with the 8 v_cmp masks hoisted out of the loop.
__global__ void __launch_bounds__(256) k_out(
    const float* __restrict__ bias, const float* __restrict__ gamma,
    const float* __restrict__ beta, const float* __restrict__ mean,
    const float* __restrict__ var, const int* __restrict__ ring,
    const unsigned int* __restrict__ smax_keys, float* __restrict__ out) {
  const int b = blockIdx.z;
  const int og = blockIdx.y;  // 32-channel group
  const int n0 = blockIdx.x * 1024;

  __shared__ __align__(16) float ymax[32 * NR];  // [oo][r]
  if (threadIdx.x < 32 * NR) {
    const int oo = (int)threadIdx.x >> 2;
    const int r = (int)threadIdx.x & 3;
    const int o = og * 32 + oo;
    const int t = r * DOUT + o;
    const unsigned int key = smax_keys[(size_t)b * NR * DOUT + t];
    const unsigned int u = (key & 0x80000000u) ? (key ^ 0x80000000u) : ~key;
    const float raw = __uint_as_float(u);
    const float sc = gamma[t] * rsqrtf(var[t] + BN_EPS);
    ymax[oo * NR + r] = (raw + bias[t] - mean[t]) * sc + beta[t];
  }
  __syncthreads();

  const int n = n0 + (int)threadIdx.x * 4;
  const int4 rg = *(const int4*)&ring[(size_t)b * NN + n];
  // hoisted 2-bit selector masks (become SGPR-pair lane masks)
  const bool ax = rg.x & 1, bx = rg.x & 2;
  const bool ay = rg.y & 1, by = rg.y & 2;
  const bool az = rg.z & 1, bz = rg.z & 2;
  const bool aw = rg.w & 1, bw = rg.w & 2;
  float* orow = out + ((size_t)b * DOUT + og * 32) * NN + n;

#pragma unroll 8
  for (int oo = 0; oo < 32; ++oo) {
    const floatx4 L = *(const floatx4*)&ymax[oo * NR];  // uniform broadcast
    nfloat4 v;
    { float lo = ax ? L.y : L.x, hi = ax ? L.w : L.z; v.x = bx ? hi : lo; }
    { float lo = ay ? L.y : L.x, hi = ay ? L.w : L.z; v.y = by ? hi : lo; }
    { float lo = az ? L.y : L.x, hi = az ? L.w : L.z; v.z = bz ? hi : lo; }
    { float lo = aw ? L.y : L.x, hi = aw ? L.w : L.z; v.w = bw ? hi : lo; }
    __builtin_nontemporal_store(v, (nfloat4*)(orow + (size_t)oo * NN));
  }
}

// ---------------------------------------------------------------------------
extern "C" void kernel_launch(void* const* d_in, const int* in_sizes, int n_in,
                              void* d_out, int out_size, void* d_ws, size_t ws_size,
                              hipStream_t stream) {
  const float* x = (const float*)d_in[0];
  const int* ring = (const int*)d_in[1];
  const float* W = (const float*)d_in[2];
  const float* bias = (const float*)d_in[3];
  const float* gamma = (const float*)d_in[4];
  const float* beta = (const float*)d_in[5];
  const float* mean = (const float*)d_in[6];
  const float* var = (const float*)d_in[7];
  float* out = (float*)d_out;

  unsigned int* keys = (unsigned int*)d_ws;

  // zero smax keys (key 0 decodes below every real key)
  (void)hipMemsetAsync(keys, 0, (size_t)BB * NR * DOUT * 4, stream);

  k_compute<<<dim3(NN / 256, BB), 256, 0, stream>>>(x, W, ring, keys);
  k_out<<<dim3(NN / 1024, DOUT / 32, BB), 256, 0, stream>>>(bias, gamma, beta, mean,
                                                            var, ring, keys, out);
}